// Round 2
// baseline (189.427 us; speedup 1.0000x reference)
//
#include <hip/hip_runtime.h>
#include <hip/hip_bf16.h>
#include <math.h>

#define N_ROWS 8192
#define DIM 256
#define NCLS 128
// scale folded into normalized rows: sqrt((1/0.07) * log2(e))
#define ROW_SCALE 4.539816f
#define CLAMP_Y 14.426950408889634f   // 10 * log2(e)
#define LN2F 0.6931471805599453f

typedef short bf16x8 __attribute__((ext_vector_type(8)));
typedef float f32x4 __attribute__((ext_vector_type(4)));

#define AS1 __attribute__((address_space(1)))
#define AS3 __attribute__((address_space(3)))

__device__ __forceinline__ void load16_to_lds(const void* g, void* lds) {
  // LDS dest = wave-uniform base + lane*16 (HW rule); gptr is per-lane
  __builtin_amdgcn_global_load_lds((const AS1 void*)g, (AS3 void*)lds, 16, 0, 0);
}

__device__ __forceinline__ unsigned short f2bf(float x) {
  union { __hip_bfloat16 b; unsigned short u; } cv;
  cv.b = __float2bfloat16(x);
  return cv.u;
}

__device__ __forceinline__ float fast_exp2(float x) {
#if __has_builtin(__builtin_amdgcn_exp2f)
  return __builtin_amdgcn_exp2f(x);
#else
  return exp2f(x);
#endif
}

// ---------------- label histogram: 1 block, LDS bins, no global pre-zero ----
__global__ __launch_bounds__(256) void hist_kernel(const int* __restrict__ labels,
                                                   int* __restrict__ counts) {
  __shared__ int h[NCLS];
  if (threadIdx.x < NCLS) h[threadIdx.x] = 0;
  __syncthreads();
  for (int i = threadIdx.x; i < N_ROWS; i += 256) atomicAdd(&h[labels[i]], 1);
  __syncthreads();
  if (threadIdx.x < NCLS) counts[threadIdx.x] = h[threadIdx.x];
}

// ---------------- row-normalize*ROW_SCALE -> bf16, and zero S/P -------------
__global__ __launch_bounds__(256) void normalize_kernel(const float* __restrict__ f,
                                                        unsigned short* __restrict__ fnb,
                                                        float* __restrict__ S,
                                                        float* __restrict__ P) {
  const int row = blockIdx.x * 4 + (threadIdx.x >> 6);
  const int l = threadIdx.x & 63;
  const float4 v = ((const float4*)(f + (size_t)row * DIM))[l];
  float ss = v.x * v.x + v.y * v.y + v.z * v.z + v.w * v.w;
#pragma unroll
  for (int m = 32; m >= 1; m >>= 1) ss += __shfl_xor(ss, m, 64);
  const float inv = ROW_SCALE / fmaxf(sqrtf(ss), 1e-6f);
  ushort4 o;
  o.x = f2bf(v.x * inv);
  o.y = f2bf(v.y * inv);
  o.z = f2bf(v.z * inv);
  o.w = f2bf(v.w * inv);
  ((ushort4*)(fnb + (size_t)row * DIM))[l] = o;
  if (l == 0) { S[row] = 0.f; P[row] = 0.f; }
}

// ---------------- upper-triangle pair GEMM + exp/positive reductions --------
// 2080 blocks, one 128x128 (bi,bj) pair each (bi<=bj). Off-diagonal blocks
// feed BOTH row sums (rows of bi) and, via symmetry, column sums (rows of bj).
// LDS: A[128][32] + B[128][32] bf16 = 16 KB, single-buffered, 2 barriers/kt.
// Accumulator is y = sim*log2(e) directly (scale folded into fnb); epilogue
// is med3-clamp + v_exp2 + label-match adds. Diagonal elements contribute
// exactly e=1 / y=CLAMP_Y, corrected in finalize.
__global__ __launch_bounds__(256) void simloss_pair(
    const unsigned short* __restrict__ fnb, const int* __restrict__ labels,
    float* __restrict__ S, float* __restrict__ P) {
  __shared__ __align__(16) unsigned short Ash[128 * 32];  // 8 KB
  __shared__ __align__(16) unsigned short Bsh[128 * 32];  // 8 KB

  const int tid = threadIdx.x;
  const int w = tid >> 6;   // wave 0..3
  const int l = tid & 63;
  const int wr = w >> 1;    // wave row -> 64 rows
  const int wc = w & 1;     // wave col -> 64 cols
  const int ln15 = l & 15;
  const int q = l >> 4;

  // decode linear triangle index -> (bi, bj), bi<=bj (uniform scalar loop)
  int p = blockIdx.x, bi = 0;
  while (p >= 64 - bi) { p -= 64 - bi; ++bi; }
  const int bj = bi + p;
  const int ibase = bi * 128, jbase = bj * 128;

  f32x4 acc[4][4];
#pragma unroll
  for (int mi = 0; mi < 4; ++mi)
#pragma unroll
    for (int ni = 0; ni < 4; ++ni) acc[mi][ni] = (f32x4)0.0f;

  for (int kt = 0; kt < 8; ++kt) {
    __syncthreads();  // LDS consumed by previous iteration
    // wave w stages rows [w*32, w*32+32) of both A(bi) and B(bj) K-slices.
    // 16B chunk pc of row r holds source chunk pc ^ ((r>>1)&3)  (2-way free)
#pragma unroll
    for (int r = 0; r < 2; ++r) {
      const int off = r * 1024 + l * 16;
      const int row = w * 32 + (off >> 6);
      const int c = ((off >> 4) & 3) ^ ((row >> 1) & 3);
      const size_t gofs = (size_t)row * 512 + (size_t)kt * 64 + (size_t)c * 16;
      load16_to_lds((const char*)fnb + (size_t)ibase * 512 + gofs,
                    (char*)Ash + w * 2048 + r * 1024);
      load16_to_lds((const char*)fnb + (size_t)jbase * 512 + gofs,
                    (char*)Bsh + w * 2048 + r * 1024);
    }
    __syncthreads();  // staging complete (compiler drains vmcnt before barrier)

    bf16x8 af[4], bfr[4];
#pragma unroll
    for (int mi = 0; mi < 4; ++mi) {
      const int row = wr * 64 + mi * 16 + ln15;
      const int c = q ^ ((row >> 1) & 3);
      af[mi] = *(const bf16x8*)((const char*)Ash + row * 64 + c * 16);
    }
#pragma unroll
    for (int ni = 0; ni < 4; ++ni) {
      const int n = wc * 64 + ni * 16 + ln15;
      const int c = q ^ ((n >> 1) & 3);
      bfr[ni] = *(const bf16x8*)((const char*)Bsh + n * 64 + c * 16);
    }
#pragma unroll
    for (int mi = 0; mi < 4; ++mi)
#pragma unroll
      for (int ni = 0; ni < 4; ++ni)
        acc[mi][ni] = __builtin_amdgcn_mfma_f32_16x16x32_bf16(af[mi], bfr[ni],
                                                              acc[mi][ni], 0, 0, 0);
  }

  // ---- epilogue ----
  int labI[16], labJ[4];
#pragma unroll
  for (int mi = 0; mi < 4; ++mi)
#pragma unroll
    for (int rg = 0; rg < 4; ++rg)
      labI[mi * 4 + rg] = labels[ibase + wr * 64 + mi * 16 + q * 4 + rg];
#pragma unroll
  for (int ni = 0; ni < 4; ++ni)
    labJ[ni] = labels[jbase + wc * 64 + ni * 16 + ln15];

  float rs[16], rp[16], cs[4], cp[4];
#pragma unroll
  for (int t = 0; t < 16; ++t) { rs[t] = 0.f; rp[t] = 0.f; }
#pragma unroll
  for (int t = 0; t < 4; ++t) { cs[t] = 0.f; cp[t] = 0.f; }

#pragma unroll
  for (int mi = 0; mi < 4; ++mi)
#pragma unroll
    for (int ni = 0; ni < 4; ++ni)
#pragma unroll
      for (int rg = 0; rg < 4; ++rg) {
        const float y = acc[mi][ni][rg];
        const float yc = fminf(CLAMP_Y, fmaxf(-CLAMP_Y, y));  // -> v_med3
        const float e = fast_exp2(yc - CLAMP_Y);
        const float pv = (labJ[ni] == labI[mi * 4 + rg]) ? yc : 0.0f;
        rs[mi * 4 + rg] += e;
        rp[mi * 4 + rg] += pv;
        cs[ni] += e;
        cp[ni] += pv;
      }

  // row sums: reduce across the 16 lanes of each quad
#pragma unroll
  for (int m = 1; m <= 8; m <<= 1)
#pragma unroll
    for (int t = 0; t < 16; ++t) {
      rs[t] += __shfl_xor(rs[t], m, 64);
      rp[t] += __shfl_xor(rp[t], m, 64);
    }
  if (ln15 == 0) {
#pragma unroll
    for (int t = 0; t < 16; ++t) {
      const int row = ibase + wr * 64 + (t >> 2) * 16 + q * 4 + (t & 3);
      atomicAdd(&S[row], rs[t]);
      atomicAdd(&P[row], rp[t]);
    }
  }

  if (bi != bj) {
    // column sums -> rows of bj (symmetry): reduce across quads
#pragma unroll
    for (int m = 16; m <= 32; m <<= 1)
#pragma unroll
      for (int t = 0; t < 4; ++t) {
        cs[t] += __shfl_xor(cs[t], m, 64);
        cp[t] += __shfl_xor(cp[t], m, 64);
      }
    if (q == 0) {
#pragma unroll
      for (int ni = 0; ni < 4; ++ni) {
        const int col = jbase + wc * 64 + ni * 16 + ln15;
        atomicAdd(&S[col], cs[ni]);
        atomicAdd(&P[col], cp[ni]);
      }
    }
  }
}

// ---------------- finalize: per-row loss + scalar mean ----------------
__global__ __launch_bounds__(1024) void finalize_kernel(
    const float* __restrict__ S, const float* __restrict__ P,
    const int* __restrict__ labels, const int* __restrict__ counts,
    float* __restrict__ out) {
  float lsum = 0.f, vsum = 0.f;
  for (int i = threadIdx.x; i < N_ROWS; i += 1024) {
    const int cnt = counts[labels[i]] - 1;  // positives excluding self
    if (cnt > 0) {
      const float lse = 10.0f + logf(S[i] - 1.0f);       // remove diag e=1
      const float psum = P[i] * LN2F - 10.0f;            // de-scale, remove diag
      lsum += lse - psum / (float)cnt;                   // -mean_log_prob_pos
      vsum += 1.0f;
    }
  }
#pragma unroll
  for (int m = 32; m >= 1; m >>= 1) {
    lsum += __shfl_xor(lsum, m, 64);
    vsum += __shfl_xor(vsum, m, 64);
  }
  __shared__ float ls[16], vs[16];
  const int wv = threadIdx.x >> 6;
  if ((threadIdx.x & 63) == 0) { ls[wv] = lsum; vs[wv] = vsum; }
  __syncthreads();
  if (threadIdx.x == 0) {
    float L = 0.f, V = 0.f;
    for (int k = 0; k < 16; ++k) { L += ls[k]; V += vs[k]; }
    out[0] = (V > 0.f) ? (L / fmaxf(V, 1.0f)) : 0.f;
  }
}

extern "C" void kernel_launch(void* const* d_in, const int* in_sizes, int n_in,
                              void* d_out, int out_size, void* d_ws, size_t ws_size,
                              hipStream_t stream) {
  const float* feat = (const float*)d_in[0];
  const int* labels = (const int*)d_in[1];
  float* out = (float*)d_out;

  char* ws = (char*)d_ws;
  unsigned short* fnb = (unsigned short*)ws;            // bf16 [8192][256], 4 MB
  float* S = (float*)(ws + (size_t)N_ROWS * DIM * 2);   // [8192]
  float* P = S + N_ROWS;                                // [8192]
  int* counts = (int*)(P + N_ROWS);                     // [128]

  normalize_kernel<<<N_ROWS / 4, 256, 0, stream>>>(feat, fnb, S, P);
  hist_kernel<<<1, 256, 0, stream>>>(labels, counts);

  simloss_pair<<<64 * 65 / 2, 256, 0, stream>>>(fnb, labels, S, P);

  finalize_kernel<<<1, 1024, 0, stream>>>(S, P, labels, counts, out);
}

// Round 3
// 117.552 us; speedup vs baseline: 1.6114x; 1.6114x over previous
//
#include <hip/hip_runtime.h>
#include <hip/hip_bf16.h>
#include <math.h>

#define N_ROWS 8192
#define DIM 256
#define NCLS 128
// scale folded into normalized rows: sqrt((1/0.07) * log2(e))
#define ROW_SCALE 4.539816f
#define CLAMP_Y 14.426950408889634f   // 10 * log2(e)
#define LN2F 0.6931471805599453f

typedef short bf16x8 __attribute__((ext_vector_type(8)));
typedef float f32x4 __attribute__((ext_vector_type(4)));

#define AS1 __attribute__((address_space(1)))
#define AS3 __attribute__((address_space(3)))

__device__ __forceinline__ void load16_to_lds(const void* g, void* lds) {
  // LDS dest = wave-uniform base + lane*16 (HW rule); gptr is per-lane
  __builtin_amdgcn_global_load_lds((const AS1 void*)g, (AS3 void*)lds, 16, 0, 0);
}

__device__ __forceinline__ unsigned short f2bf(float x) {
  union { __hip_bfloat16 b; unsigned short u; } cv;
  cv.b = __float2bfloat16(x);
  return cv.u;
}

__device__ __forceinline__ float fast_exp2(float x) {
#if __has_builtin(__builtin_amdgcn_exp2f)
  return __builtin_amdgcn_exp2f(x);
#else
  return exp2f(x);
#endif
}

// ---------------- row-normalize*ROW_SCALE -> bf16, zero S/P -----------------
__global__ __launch_bounds__(256) void normalize_kernel(const float* __restrict__ f,
                                                        unsigned short* __restrict__ fnb,
                                                        float* __restrict__ S,
                                                        float* __restrict__ P) {
  const int row = blockIdx.x * 4 + (threadIdx.x >> 6);
  const int l = threadIdx.x & 63;
  const float4 v = ((const float4*)(f + (size_t)row * DIM))[l];
  float ss = v.x * v.x + v.y * v.y + v.z * v.z + v.w * v.w;
#pragma unroll
  for (int m = 32; m >= 1; m >>= 1) ss += __shfl_xor(ss, m, 64);
  const float inv = ROW_SCALE / fmaxf(sqrtf(ss), 1e-6f);
  ushort4 o;
  o.x = f2bf(v.x * inv);
  o.y = f2bf(v.y * inv);
  o.z = f2bf(v.z * inv);
  o.w = f2bf(v.w * inv);
  ((ushort4*)(fnb + (size_t)row * DIM))[l] = o;
  if (l == 0) { S[row] = 0.f; P[row] = 0.f; }
}

// ---------------- triangular-strip GEMM + exp/positive reductions -----------
// 544 blocks: block = (bi, chunk) where row-tile bi (128 rows, A resident in
// LDS) processes up to 4 j-tiles bj = bi+4*chunk .. from the upper triangle.
// Off-diagonal tiles feed BOTH row sums (rows of bi) and, via symmetry,
// column sums (rows of bj). Row sums persist in registers across the block
// (one atomic flush); col sums are wr-pair-combined in LDS before atomics.
// Accumulator is y = sim*log2(e) (scale folded into fnb); diagonal elements
// contribute exactly e=1 / y=CLAMP_Y, corrected in finalize.
__global__ __launch_bounds__(256, 2) void simloss_tri(
    const unsigned short* __restrict__ fnb, const int* __restrict__ labels,
    float* __restrict__ S, float* __restrict__ P) {
  __shared__ __align__(16) unsigned short Atile[128 * 256];  // 64 KB
  __shared__ __align__(16) unsigned short Bsh[128 * 32];     // 8 KB
  __shared__ float redbuf[128][2];                           // 1 KB cross-wave

  const int tid = threadIdx.x;
  const int w = tid >> 6;   // wave 0..3
  const int l = tid & 63;
  const int wr = w >> 1;    // wave row -> 64 rows
  const int wc = w & 1;     // wave col -> 64 cols
  const int ln15 = l & 15;
  const int q = l >> 4;

  // decode blockIdx.x -> (bi, chunk); row bi has ceil((64-bi)/4) chunks
  int b = blockIdx.x, bi;
  for (bi = 0; bi < 64; ++bi) {
    const int nch = (64 - bi + 3) >> 2;
    if (b < nch) break;
    b -= nch;
  }
  const int ibase = bi * 128;
  const int j0 = bi + b * 4;                      // first j-tile
  const int jn = (64 - j0 < 4) ? (64 - j0) : 4;   // tiles this block

  // ---- stage A [128][256] bf16; 16B chunk c of row r stored at c^(r&7)
  {
    const char* gbase = (const char*)fnb;
#pragma unroll
    for (int r = 0; r < 16; ++r) {
      const int off = r * 4096 + w * 1024 + l * 16;
      const int row = off >> 9;                    // 512 B per row
      const int c = ((off >> 4) & 31) ^ (row & 7);
      load16_to_lds(gbase + (size_t)(ibase + row) * 512 + c * 16,
                    (char*)Atile + r * 4096 + w * 1024);
    }
  }

  int rowlab[16];
#pragma unroll
  for (int mi = 0; mi < 4; ++mi)
#pragma unroll
    for (int rg = 0; rg < 4; ++rg)
      rowlab[mi * 4 + rg] = labels[ibase + wr * 64 + mi * 16 + q * 4 + rg];

  float rs[16], rp[16];
#pragma unroll
  for (int t = 0; t < 16; ++t) { rs[t] = 0.f; rp[t] = 0.f; }

  for (int jt = 0; jt < jn; ++jt) {
    const int bj = j0 + jt;
    const int jbase = bj * 128;
    int labJ[4];
#pragma unroll
    for (int ni = 0; ni < 4; ++ni)
      labJ[ni] = labels[jbase + wc * 64 + ni * 16 + ln15];

    f32x4 acc[4][4];
#pragma unroll
    for (int mi = 0; mi < 4; ++mi)
#pragma unroll
      for (int ni = 0; ni < 4; ++ni) acc[mi][ni] = (f32x4)0.0f;

    for (int kt = 0; kt < 8; ++kt) {
      __syncthreads();  // LDS consumed by previous iteration / A-loads drain
      // stage B [128][32]; 16B chunk c of row n stored at c^((n>>1)&3)
#pragma unroll
      for (int r = 0; r < 2; ++r) {
        const int off = r * 1024 + l * 16;
        const int row = w * 32 + (off >> 6);       // 64 B per row
        const int c = ((off >> 4) & 3) ^ ((row >> 1) & 3);
        load16_to_lds((const char*)fnb + (size_t)(jbase + row) * 512 +
                          (size_t)kt * 64 + c * 16,
                      (char*)Bsh + w * 2048 + r * 1024);
      }
      __syncthreads();  // staging complete

      bf16x8 af[4], bfr[4];
#pragma unroll
      for (int mi = 0; mi < 4; ++mi) {
        const int row = wr * 64 + mi * 16 + ln15;
        const int c = (kt * 4 + q) ^ (row & 7);
        af[mi] = *(const bf16x8*)((const char*)Atile + row * 512 + c * 16);
      }
#pragma unroll
      for (int ni = 0; ni < 4; ++ni) {
        const int n = wc * 64 + ni * 16 + ln15;
        const int c = q ^ ((n >> 1) & 3);
        bfr[ni] = *(const bf16x8*)((const char*)Bsh + n * 64 + c * 16);
      }
#pragma unroll
      for (int mi = 0; mi < 4; ++mi)
#pragma unroll
        for (int ni = 0; ni < 4; ++ni)
          acc[mi][ni] = __builtin_amdgcn_mfma_f32_16x16x32_bf16(af[mi], bfr[ni],
                                                                acc[mi][ni], 0, 0, 0);
    }

    // ---- epilogue: exp-sum + positive-sim accumulate (rows + cols) ----
    float cs[4], cp[4];
#pragma unroll
    for (int t = 0; t < 4; ++t) { cs[t] = 0.f; cp[t] = 0.f; }
#pragma unroll
    for (int mi = 0; mi < 4; ++mi)
#pragma unroll
      for (int ni = 0; ni < 4; ++ni)
#pragma unroll
        for (int rg = 0; rg < 4; ++rg) {
          const float y = acc[mi][ni][rg];
          const float yc = fminf(CLAMP_Y, fmaxf(-CLAMP_Y, y));  // v_med3
          const float e = fast_exp2(yc - CLAMP_Y);
          const float pv = (labJ[ni] == rowlab[mi * 4 + rg]) ? yc : 0.0f;
          rs[mi * 4 + rg] += e;
          rp[mi * 4 + rg] += pv;
          cs[ni] += e;
          cp[ni] += pv;
        }

    // col sums -> rows of bj via symmetry (skip diagonal tile)
#pragma unroll
    for (int m = 16; m <= 32; m <<= 1)
#pragma unroll
      for (int t = 0; t < 4; ++t) {
        cs[t] += __shfl_xor(cs[t], m, 64);
        cp[t] += __shfl_xor(cp[t], m, 64);
      }
    if (wr == 1 && q == 0) {
#pragma unroll
      for (int ni = 0; ni < 4; ++ni) {
        const int cl = wc * 64 + ni * 16 + ln15;
        redbuf[cl][0] = cs[ni];
        redbuf[cl][1] = cp[ni];
      }
    }
    __syncthreads();
    if (wr == 0 && q == 0 && bj != bi) {
#pragma unroll
      for (int ni = 0; ni < 4; ++ni) {
        const int cl = wc * 64 + ni * 16 + ln15;
        atomicAdd(&S[jbase + cl], cs[ni] + redbuf[cl][0]);
        atomicAdd(&P[jbase + cl], cp[ni] + redbuf[cl][1]);
      }
    }
  }

  // ---- row-sum flush: 16-lane reduce, wc-pair combine in LDS, atomics ----
#pragma unroll
  for (int m = 1; m <= 8; m <<= 1)
#pragma unroll
    for (int t = 0; t < 16; ++t) {
      rs[t] += __shfl_xor(rs[t], m, 64);
      rp[t] += __shfl_xor(rp[t], m, 64);
    }
  __syncthreads();  // drain last col-combine redbuf reads
  if (wc == 1 && ln15 == 0) {
#pragma unroll
    for (int t = 0; t < 16; ++t) {
      const int rl = wr * 64 + (t >> 2) * 16 + q * 4 + (t & 3);
      redbuf[rl][0] = rs[t];
      redbuf[rl][1] = rp[t];
    }
  }
  __syncthreads();
  if (wc == 0 && ln15 == 0) {
#pragma unroll
    for (int t = 0; t < 16; ++t) {
      const int rl = wr * 64 + (t >> 2) * 16 + q * 4 + (t & 3);
      atomicAdd(&S[ibase + rl], rs[t] + redbuf[rl][0]);
      atomicAdd(&P[ibase + rl], rp[t] + redbuf[rl][1]);
    }
  }
}

// ---------------- finalize: label hist (LDS) + per-row loss + mean ----------
__global__ __launch_bounds__(1024) void finalize_kernel(
    const float* __restrict__ S, const float* __restrict__ P,
    const int* __restrict__ labels, float* __restrict__ out) {
  __shared__ int h[NCLS];
  if (threadIdx.x < NCLS) h[threadIdx.x] = 0;
  __syncthreads();
  for (int i = threadIdx.x; i < N_ROWS; i += 1024) atomicAdd(&h[labels[i]], 1);
  __syncthreads();

  float lsum = 0.f, vsum = 0.f;
  for (int i = threadIdx.x; i < N_ROWS; i += 1024) {
    const int cnt = h[labels[i]] - 1;  // positives excluding self
    if (cnt > 0) {
      const float lse = 10.0f + logf(S[i] - 1.0f);   // remove diag e=1
      const float psum = P[i] * LN2F - 10.0f;        // de-scale, remove diag
      lsum += lse - psum / (float)cnt;               // -mean_log_prob_pos
      vsum += 1.0f;
    }
  }
#pragma unroll
  for (int m = 32; m >= 1; m >>= 1) {
    lsum += __shfl_xor(lsum, m, 64);
    vsum += __shfl_xor(vsum, m, 64);
  }
  __shared__ float ls[16], vs[16];
  const int wv = threadIdx.x >> 6;
  if ((threadIdx.x & 63) == 0) { ls[wv] = lsum; vs[wv] = vsum; }
  __syncthreads();
  if (threadIdx.x == 0) {
    float L = 0.f, V = 0.f;
    for (int k = 0; k < 16; ++k) { L += ls[k]; V += vs[k]; }
    out[0] = (V > 0.f) ? (L / fmaxf(V, 1.0f)) : 0.f;
  }
}

extern "C" void kernel_launch(void* const* d_in, const int* in_sizes, int n_in,
                              void* d_out, int out_size, void* d_ws, size_t ws_size,
                              hipStream_t stream) {
  const float* feat = (const float*)d_in[0];
  const int* labels = (const int*)d_in[1];
  float* out = (float*)d_out;

  char* ws = (char*)d_ws;
  unsigned short* fnb = (unsigned short*)ws;            // bf16 [8192][256], 4 MB
  float* S = (float*)(ws + (size_t)N_ROWS * DIM * 2);   // [8192]
  float* P = S + N_ROWS;                                // [8192]

  normalize_kernel<<<N_ROWS / 4, 256, 0, stream>>>(feat, fnb, S, P);
  simloss_tri<<<544, 256, 0, stream>>>(fnb, labels, S, P);
  finalize_kernel<<<1, 1024, 0, stream>>>(S, P, labels, out);
}